// Round 9
// baseline (384.942 us; speedup 1.0000x reference)
//
#include <hip/hip_runtime.h>
#include <math.h>

#define LEAKY(x) ((x) >= 0.f ? (x) : 0.3f*(x))

// ---- workspace float offsets ----
#define G_OFF   0         // 648     extracted g~ (72x9)
#define IM_OFF  648       // 7776    im (b,ch,81)
#define LAM_OFF 8424      // 32      lambda per batch
#define WB_OFF  8456      // 2592    w branch (b,81)
#define YBR_OFF 11048     // 82944   y branch (b,81,32)
#define X2_OFF  757544    // 331776  conv15 out (b,18,18,32)

#define OUT0 106272       // elements in output 0; cs_out follows

// ======================= prep =======================
__global__ __launch_bounds__(256) void prep_kernel(
    const float* __restrict__ inp, const float* __restrict__ mat,
    const float* __restrict__ w1_k, const float* __restrict__ w1_b,
    const float* __restrict__ x1_k, const float* __restrict__ x1_b,
    const float* __restrict__ y17_k, const float* __restrict__ y17_b,
    const float* __restrict__ y71_k, const float* __restrict__ y71_b,
    const float* __restrict__ yc_k, const float* __restrict__ yc_b,
    const float* __restrict__ d1_k, const float* __restrict__ d2_k,
    const float* __restrict__ h1_w, const float* __restrict__ h1_b,
    const float* __restrict__ h2_w, const float* __restrict__ h2_b,
    const float* __restrict__ h3_w, const float* __restrict__ h3_b,
    float* __restrict__ ws)
{
    int t = threadIdx.x;
    if (blockIdx.x == 0) {
        // extract separable factor: g[i][a] = mat[i*72, a*9] / sqrt(mat[0,0])
        float rs = rsqrtf(mat[0]);
        for (int u = t; u < 648; u += 256) {
            int i = u / 9, a = u % 9;
            ws[G_OFF + u] = mat[(size_t)(i*72)*81 + a*9] * rs;
        }
        return;
    }
    int b = blockIdx.x - 1;
    __shared__ float sin_[243];
    __shared__ float cm[27];
    __shared__ float cat[5184];
    __shared__ float z1[108];
    __shared__ float z2[24];
    __shared__ float v1[24];
    __shared__ float v2[12];

    const float BN  = 1.0f / sqrtf(1.001f);
    const float BN2 = BN * BN;

    for (int u = t; u < 243; u += 256) sin_[u] = inp[b*243 + u];
    __syncthreads();

    // w branch (t<81), colmax (81..107), d1 conv (128..235)
    if (t < 81) {
        float s = w1_b[0];
        for (int i = 0; i < 3; ++i) s += sin_[t*3+i] * w1_k[i];
        ws[WB_OFF + b*81 + t] = LEAKY(s);
    } else if (t < 108) {
        int u = t - 81;                       // c*3+ch
        float m = 0.f;
        for (int r = 0; r < 9; ++r) m = fmaxf(m, fabsf(sin_[r*27 + u]));
        cm[u] = 0.001f + m;
    }
    if (t >= 128 && t < 236) {
        int u = t - 128;                      // oy*36 + ox*12 + o
        int o = u % 12, ox = (u/12) % 3, oy = u/36;
        float s = 0.f;
        for (int kh = 0; kh < 5; ++kh) {
            int iy = oy*3 - 1 + kh;
            if (iy < 0 || iy > 8) continue;
            for (int kw = 0; kw < 5; ++kw) {
                int ix = ox*3 - 1 + kw;
                if (ix < 0 || ix > 8) continue;
                for (int i = 0; i < 3; ++i)
                    s += sin_[(iy*9+ix)*3 + i] * d1_k[((kh*5+kw)*3 + i)*12 + o];
            }
        }
        z1[u] = LEAKY(BN2 * s);
    }
    __syncthreads();

    // im = leaky(conv1x1(inp / colmax)) ; layout (b,ch,81)
    if (t < 243) {
        int o = t / 81, p = t % 81;
        int c = p % 9;
        float s = x1_b[o];
        for (int i = 0; i < 3; ++i)
            s += (sin_[p*3+i] / cm[c*3+i]) * x1_k[i*3 + o];
        ws[IM_OFF + (b*3 + o)*81 + p] = LEAKY(s);
    }
    __syncthreads();

    // d2 conv: 3x3x12 -> 1x1x24 (kernel rows/cols 1..3 valid)
    if (t < 24) {
        float s = 0.f;
        for (int kh = 1; kh < 4; ++kh)
            for (int kw = 1; kw < 4; ++kw)
                for (int i = 0; i < 12; ++i)
                    s += z1[((kh-1)*3 + (kw-1))*12 + i] * d2_k[((kh*5+kw)*12 + i)*24 + t];
        z2[t] = LEAKY(BN * s);
    }
    __syncthreads();
    if (t < 24) {
        float s = h1_b[t];
        for (int i = 0; i < 24; ++i) s += z2[i] * h1_w[i*24 + t];
        v1[t] = s;
    }
    __syncthreads();
    if (t < 12) {
        float s = h2_b[t];
        for (int i = 0; i < 24; ++i) s += v1[i] * h2_w[i*12 + t];
        v2[t] = s;
    }
    __syncthreads();
    if (t == 0) {
        float s = h3_b[0];
        for (int i = 0; i < 12; ++i) s += v2[i] * h3_w[i];
        ws[LAM_OFF + b] = 0.01f / (1.f + expf(-s));   // 0.1*sigmoid * 0.1
    }

    // y branch: cat = [y1(32) | y2(32)] per position
    for (int u = t; u < 5184; u += 256) {
        int pos = u / 64, i = u % 64;
        int r = pos / 9, c = pos % 9;
        float s;
        if (i < 32) {
            s = y17_b[i];
            for (int kw = 0; kw < 7; ++kw) {
                int cc = c - 3 + kw;
                if (cc < 0 || cc > 8) continue;
                for (int ii = 0; ii < 3; ++ii)
                    s += sin_[(r*9+cc)*3 + ii] * y17_k[(kw*3+ii)*32 + i];
            }
        } else {
            int i2 = i - 32;
            s = y71_b[i2];
            for (int kh = 0; kh < 7; ++kh) {
                int rr = r - 3 + kh;
                if (rr < 0 || rr > 8) continue;
                for (int ii = 0; ii < 3; ++ii)
                    s += sin_[(rr*9+c)*3 + ii] * y71_k[(kh*3+ii)*32 + i2];
            }
        }
        cat[pos*64 + i] = s;
    }
    __syncthreads();
    for (int u = t; u < 2592; u += 256) {
        int pos = u / 32, o = u % 32;
        float s = yc_b[o];
        for (int i = 0; i < 64; ++i) s += cat[pos*64 + i] * yc_k[i*32 + o];
        ws[YBR_OFF + (b*81 + pos)*32 + o] = LEAKY(s);
    }
}

// ======================= FISTA (unchanged from R8, hardware-verified) =======
// 576 threads = 9 waves. t = j*8 + gg: lane owns rows i = 8*s + gg (s=0..8)
// of column j = 8*w + rr. Toeplitz band on both row and column sides.
// 2 barriers/iter; VGPR 52, no spill; 152.9us measured.

#define DPP_XOR1 0xB1   // quad_perm {1,0,3,2}
#define DPP_XOR2 0x4E   // quad_perm {2,3,0,1}
#define DPP_HM   0x141  // row_half_mirror (cross-quad within 8; quads uniform)
#define DPP_ROR8 0x128  // row_ror:8 == lane xor 8 within 16-lane row

template<int CTRL>
__device__ __forceinline__ float dppadd(float v) {
    return v + __int_as_float(__builtin_amdgcn_update_dpp(
        0, __float_as_int(v), CTRL, 0xF, 0xF, true));
}

#define STEPMID(s,sm,sp) { \
    float re = gm*q##sm + g0*q##s + gp*q##sp; \
    float wv = Yv##s + re; \
    float cl = fminf(fmaxf(wv, -lam), lam); \
    float yn = wv - cl; \
    float yx = yn + cmom*(yn - Yl##s); \
    Yl##s = yn; Yv##s = yx; \
    u##sm += yx*gm; u##s += yx*g0; u##sp += yx*gp; }
#define STEP0 { \
    float re = g0*q0 + gp*q1; \
    float wv = Yv0 + re; \
    float cl = fminf(fmaxf(wv, -lam), lam); \
    float yn = wv - cl; \
    float yx = yn + cmom*(yn - Yl0); \
    Yl0 = yn; Yv0 = yx; \
    u0 += yx*g0; u1 += yx*gp; }
#define STEP8 { \
    float re = gm*q7 + g0*q8; \
    float wv = Yv8 + re; \
    float cl = fminf(fmaxf(wv, -lam), lam); \
    float yn = wv - cl; \
    float yx = yn + cmom*(yn - Yl8); \
    Yl8 = yn; Yv8 = yx; \
    u7 += yx*gm; u8 += yx*g0; }

#define TSP(a) { float v = u##a; \
    v = dppadd<DPP_XOR1>(v); v = dppadd<DPP_XOR2>(v); v = dppadd<DPP_HM>(v); \
    float vA = v*Gjg, vB = v*Gj8; \
    spA_##a = dppadd<DPP_ROR8>(vA); spB_##a = dppadd<DPP_ROR8>(vB); }

#define QT3(a) float q##a = cmc*rm_##a + c0c*r0_##a + cpc*rp_##a;

#define OUTW(s) cs_out[(size_t)(b*5184 + (8*s+gg)*72 + j)*3 + ch] = Yl##s;

__global__ __launch_bounds__(576, 3) void fista_kernel(
    const float* __restrict__ ws, float* __restrict__ cs_out)
{
    __shared__ __align__(16) float SPm[36*108];  // 36 sets x (9 slots x 12 pad)
    __shared__ __align__(16) float Rm[108];      // R[b][a], rows of 12

    int t = threadIdx.x;
    int b = blockIdx.x / 3, ch = blockIdx.x % 3;
    const float* g = ws + G_OFF;
    float lam = ws[LAM_OFF + b];

    int j = t >> 3, gg = t & 7;      // column j, row-group gg (i = 8s+gg)
    int l = t & 63;                  // lane in wave
    int w = t >> 6;                  // wave index = j>>3
    int rr = j & 7;                  // j = 8w + rr

    // ---- row-side Toeplitz G registers ----
    float gm = g[(gg + 8)*9 + 0];    // f(gg+8)
    float g0 = g[gg*9 + 0];          // f(gg)
    float gp = g[gg*9 + 1];          // f(gg-8)

    // ---- column-side Toeplitz coeffs (qt and S band) ----
    float cmc = (w > 0) ? g[(rr + 8)*9 + 0] : 0.f;   // f(rr+8), b=w-1
    float c0c = g[rr*9 + 0];                          // f(rr),   b=w
    float cpc = (w < 8) ? g[rr*9 + 1] : 0.f;          // f(rr-8), b=w+1
    int bmr = (w > 0) ? w - 1 : 0;   // clamped row indices (coeff is 0 there)
    int bpr = (w < 8) ? w + 1 : 8;

    float Gjg = g[j*9 + gg];         // g[j][gg]  (TSP store side)
    float Gj8 = g[j*9 + 8];          // g[j][8]

    // reducer role (t < 324): ab = a*9+b pair, pp = row-set split (4 rows)
    int ab = t >> 2, pp = t & 3;
    int aa = ab / 9, bb = ab % 9;
    float im_ab = (t < 324) ? ws[IM_OFF + (b*3 + ch)*81 + ab] : 0.f;

    // init R = im (transposed: Rm[b][a] = im[a][b])
    if (t < 81) {
        Rm[(t % 9)*12 + (t / 9)] = ws[IM_OFF + (b*3 + ch)*81 + t];
    }

    float Yv0=0,Yv1=0,Yv2=0,Yv3=0,Yv4=0,Yv5=0,Yv6=0,Yv7=0,Yv8=0;
    float Yl0=0,Yl1=0,Yl2=0,Yl3=0,Yl4=0,Yl5=0,Yl6=0,Yl7=0,Yl8=0;
    float tk = 1.f;
    __syncthreads();

    for (int it = 0; it < 100; ++it) {
        float tn = 0.5f*(1.f + sqrtf(1.f + 4.f*tk*tk));
        float cmom = (tk - 1.f) / tn;
        tk = tn;

        // ---- qt[a]: 3-term band over broadcast R rows
        float4 mv0 = *(const float4*)(Rm + bmr*12);
        float4 mv1 = *(const float4*)(Rm + bmr*12 + 4);
        float  mv2 = Rm[bmr*12 + 8];
        float rm_0=mv0.x, rm_1=mv0.y, rm_2=mv0.z, rm_3=mv0.w,
              rm_4=mv1.x, rm_5=mv1.y, rm_6=mv1.z, rm_7=mv1.w, rm_8=mv2;
        float4 zv0 = *(const float4*)(Rm + w*12);
        float4 zv1 = *(const float4*)(Rm + w*12 + 4);
        float  zv2 = Rm[w*12 + 8];
        float r0_0=zv0.x, r0_1=zv0.y, r0_2=zv0.z, r0_3=zv0.w,
              r0_4=zv1.x, r0_5=zv1.y, r0_6=zv1.z, r0_7=zv1.w, r0_8=zv2;
        float4 pv0 = *(const float4*)(Rm + bpr*12);
        float4 pv1 = *(const float4*)(Rm + bpr*12 + 4);
        float  pv2 = Rm[bpr*12 + 8];
        float rp_0=pv0.x, rp_1=pv0.y, rp_2=pv0.z, rp_3=pv0.w,
              rp_4=pv1.x, rp_5=pv1.y, rp_6=pv1.z, rp_7=pv1.w, rp_8=pv2;
        QT3(0) QT3(1) QT3(2) QT3(3) QT3(4) QT3(5) QT3(6) QT3(7) QT3(8)

        // ---- y-update for 9 owned rows + u partials (3-term band)
        float u0=0,u1=0,u2=0,u3=0,u4=0,u5=0,u6=0,u7=0,u8=0;
        STEP0
        STEPMID(1,0,2) STEPMID(2,1,3) STEPMID(3,2,4) STEPMID(4,3,5)
        STEPMID(5,4,6) STEPMID(6,5,7) STEPMID(7,6,8)
        STEP8
        if (it == 99) break;

        // ---- T butterfly + S partials (j-pair folded)
        float spA_0,spA_1,spA_2,spA_3,spA_4,spA_5,spA_6,spA_7,spA_8;
        float spB_0,spB_1,spB_2,spB_3,spB_4,spB_5,spB_6,spB_7,spB_8;
        TSP(0) TSP(1) TSP(2) TSP(3) TSP(4) TSP(5) TSP(6) TSP(7) TSP(8)

        // ---- store partial sets: set = wave*4 + row; slot gg (and slot 8)
        int setb = ((t >> 6)*4 + (l >> 4))*108;
        if ((l & 8) == 0) {
            float* d = &SPm[setb + gg*12];
            ((float4*)d)[0] = make_float4(spA_0,spA_1,spA_2,spA_3);
            ((float4*)d)[1] = make_float4(spA_4,spA_5,spA_6,spA_7);
            d[8] = spA_8;
            if (gg == 0) {
                float* d2 = &SPm[setb + 96];
                ((float4*)d2)[0] = make_float4(spB_0,spB_1,spB_2,spB_3);
                ((float4*)d2)[1] = make_float4(spB_4,spB_5,spB_6,spB_7);
                d2[8] = spB_8;
            }
        }
        __syncthreads();

        // ---- reduce: only waves {bb-1, bb, bb+1} contribute to S[.][bb]
        if (t < 324) {
            float s = SPm[(bb*4 + pp)*108 + bb*12 + aa];
            if (bb > 0) s += SPm[((bb-1)*4 + pp)*108 + bb*12 + aa];
            if (bb < 8) s += SPm[((bb+1)*4 + pp)*108 + bb*12 + aa];
            s = dppadd<DPP_XOR1>(s);
            s = dppadd<DPP_XOR2>(s);
            if (pp == 0) Rm[bb*12 + aa] = im_ab - s;
        }
        __syncthreads();
    }

    // ---- output: rows 8s+gg of column j
    OUTW(0) OUTW(1) OUTW(2) OUTW(3) OUTW(4) OUTW(5) OUTW(6) OUTW(7) OUTW(8)
}

// ======================= fused c51 + c15 =======================
// One block per batch b. x1 (36x36x16 = 83KB) lives in LDS only -- never
// written to HBM. Stage 1 = c51 (5x1 conv, stride 2), barrier,
// stage 2 = c15 (1x5 conv, stride 2) -> x2 to global (layout unchanged).
__global__ __launch_bounds__(1024) void c51c15_kernel(
    const float* __restrict__ cs, const float* __restrict__ k51,
    const float* __restrict__ b51, const float* __restrict__ k15,
    const float* __restrict__ b15, float* __restrict__ x2out)
{
    __shared__ float x1s[36*36*16];   // 82944 B
    int t = threadIdx.x;
    int b = blockIdx.x;

    // stage 1: x1s[oy][ox][o]
    for (int u = t; u < 36*36*16; u += 1024) {
        int o = u & 15; int rest = u >> 4;
        int ox = rest % 36; int oy = rest / 36;
        float s = b51[o];
        int ix = ox*2;
        for (int kh = 0; kh < 5; ++kh) {
            int iy = oy*2 - 1 + kh;
            if (iy < 0 || iy >= 72) continue;
            const float* p = cs + ((size_t)(b*72 + iy)*72 + ix)*3;
            const float* kk = k51 + kh*48 + o;
            s += p[0]*kk[0] + p[1]*kk[16] + p[2]*kk[32];
        }
        x1s[u] = s;
    }
    __syncthreads();

    // stage 2: x2[oy][ox][o] -> global
    for (int u = t; u < 18*18*32; u += 1024) {
        int o = u & 31; int rest = u >> 5;
        int ox = rest % 18; int oy = rest / 18;
        float s = b15[o];
        int iy = oy*2;
        for (int kw = 0; kw < 5; ++kw) {
            int ix = ox*2 - 1 + kw;
            if (ix < 0 || ix >= 36) continue;
            const float* p = x1s + ((iy*36) + ix)*16;
            const float* kk = k15 + kw*512 + o;
            for (int i = 0; i < 16; ++i) s += p[i]*kk[i*32];
        }
        x2out[((size_t)(b*18 + oy)*18 + ox)*32 + o] = s;
    }
}

// ======================= fused c55 + x2conv + out =======================
// Block = 256 threads = 4 positions x 64 channels; grid = 2592/4 = 648.
// Phase 1: x3[pos][o] (c55) into LDS. Phase 2: the 41 output channels per
// position: q=0 w-branch copy, q=1..8 leaky(1x1 conv of x3), q>=9 y-branch
// copy. x3 never touches HBM.
__global__ __launch_bounds__(256) void c55out_kernel(
    const float* __restrict__ x2g, const float* __restrict__ k55,
    const float* __restrict__ b55, const float* __restrict__ ws,
    const float* __restrict__ x2_k, const float* __restrict__ x2_b,
    float* __restrict__ out)
{
    __shared__ float x3s[4][64];
    int t = threadIdx.x;
    int lp = t >> 6;                      // local position 0..3
    int o  = t & 63;
    int pg = blockIdx.x*4 + lp;           // global position
    int b  = pg / 81, rc = pg % 81;
    int r  = rc / 9,  c  = rc % 9;

    // phase 1: c55 at (b, r, c) channel o
    {
        float s = b55[o];
        for (int kh = 0; kh < 5; ++kh) {
            int iy = r*2 - 1 + kh;
            if (iy < 0 || iy >= 18) continue;
            for (int kw = 0; kw < 5; ++kw) {
                int ix = c*2 - 1 + kw;
                if (ix < 0 || ix >= 18) continue;
                const float* p = x2g + ((size_t)(b*18 + iy)*18 + ix)*32;
                const float* kk = k55 + (kh*5+kw)*2048 + o;
                for (int i = 0; i < 32; ++i) s += p[i]*kk[i*64];
            }
        }
        x3s[lp][o] = s;
    }
    __syncthreads();

    // phase 2: 41 outputs per position (164 active threads)
    if (t < 4*41) {
        int lp2 = t / 41, q = t % 41;
        int pg2 = blockIdx.x*4 + lp2;
        int b2  = pg2 / 81, rc2 = pg2 % 81;
        float val;
        if (q == 0) {
            val = ws[WB_OFF + b2*81 + rc2];
        } else if (q <= 8) {
            int o2 = q - 1;
            float s = x2_b[o2];
            for (int i = 0; i < 64; ++i) s += x3s[lp2][i]*x2_k[i*8 + o2];
            val = LEAKY(s);
        } else {
            val = ws[YBR_OFF + (size_t)(b2*81 + rc2)*32 + (q - 9)];
        }
        out[(size_t)pg2*41 + q] = val;
    }
}

// ======================= launch =======================
extern "C" void kernel_launch(void* const* d_in, const int* in_sizes, int n_in,
                              void* d_out, int out_size, void* d_ws, size_t ws_size,
                              hipStream_t stream) {
    const float* inp   = (const float*)d_in[0];
    const float* mat   = (const float*)d_in[1];
    const float* w1_k  = (const float*)d_in[2];
    const float* w1_b  = (const float*)d_in[3];
    const float* x1_k  = (const float*)d_in[4];
    const float* x1_b  = (const float*)d_in[5];
    const float* c51_k = (const float*)d_in[6];
    const float* c51_b = (const float*)d_in[7];
    const float* c15_k = (const float*)d_in[8];
    const float* c15_b = (const float*)d_in[9];
    const float* c55_k = (const float*)d_in[10];
    const float* c55_b = (const float*)d_in[11];
    const float* x2_k  = (const float*)d_in[12];
    const float* x2_b  = (const float*)d_in[13];
    const float* y17_k = (const float*)d_in[14];
    const float* y17_b = (const float*)d_in[15];
    const float* y71_k = (const float*)d_in[16];
    const float* y71_b = (const float*)d_in[17];
    const float* yc_k  = (const float*)d_in[18];
    const float* yc_b  = (const float*)d_in[19];
    const float* d1_k  = (const float*)d_in[20];
    const float* d2_k  = (const float*)d_in[21];
    const float* h1_w  = (const float*)d_in[22];
    const float* h1_b  = (const float*)d_in[23];
    const float* h2_w  = (const float*)d_in[24];
    const float* h2_b  = (const float*)d_in[25];
    const float* h3_w  = (const float*)d_in[26];
    const float* h3_b  = (const float*)d_in[27];

    float* ws  = (float*)d_ws;
    float* out = (float*)d_out;
    float* cs  = out + OUT0;

    hipLaunchKernelGGL(prep_kernel, dim3(33), dim3(256), 0, stream,
        inp, mat, w1_k, w1_b, x1_k, x1_b, y17_k, y17_b, y71_k, y71_b,
        yc_k, yc_b, d1_k, d2_k, h1_w, h1_b, h2_w, h2_b, h3_w, h3_b, ws);
    hipLaunchKernelGGL(fista_kernel, dim3(96), dim3(576), 0, stream, ws, cs);
    hipLaunchKernelGGL(c51c15_kernel, dim3(32), dim3(1024), 0, stream,
        cs, c51_k, c51_b, c15_k, c15_b, ws + X2_OFF);
    hipLaunchKernelGGL(c55out_kernel, dim3(648), dim3(256), 0, stream,
        ws + X2_OFF, c55_k, c55_b, ws, x2_k, x2_b, out);
}

// Round 10
// 346.725 us; speedup vs baseline: 1.1102x; 1.1102x over previous
//
#include <hip/hip_runtime.h>
#include <math.h>

#define LEAKY(x) ((x) >= 0.f ? (x) : 0.3f*(x))

// ---- workspace float offsets ----
#define G_OFF   0         // 648     extracted g~ (72x9)
#define IM_OFF  648       // 7776    im (b,ch,81)
#define LAM_OFF 8424      // 32      lambda per batch
#define WB_OFF  8456      // 2592    w branch (b,81)
#define YBR_OFF 11048     // 82944   y branch (b,81,32)
#define X2_OFF  757544    // 331776  conv15 out (b,18,18,32)

#define OUT0 106272       // elements in output 0; cs_out follows

// ======================= prep =======================
__global__ __launch_bounds__(256) void prep_kernel(
    const float* __restrict__ inp, const float* __restrict__ mat,
    const float* __restrict__ w1_k, const float* __restrict__ w1_b,
    const float* __restrict__ x1_k, const float* __restrict__ x1_b,
    const float* __restrict__ y17_k, const float* __restrict__ y17_b,
    const float* __restrict__ y71_k, const float* __restrict__ y71_b,
    const float* __restrict__ yc_k, const float* __restrict__ yc_b,
    const float* __restrict__ d1_k, const float* __restrict__ d2_k,
    const float* __restrict__ h1_w, const float* __restrict__ h1_b,
    const float* __restrict__ h2_w, const float* __restrict__ h2_b,
    const float* __restrict__ h3_w, const float* __restrict__ h3_b,
    float* __restrict__ ws)
{
    int t = threadIdx.x;
    if (blockIdx.x == 0) {
        // extract separable factor: g[i][a] = mat[i*72, a*9] / sqrt(mat[0,0])
        float rs = rsqrtf(mat[0]);
        for (int u = t; u < 648; u += 256) {
            int i = u / 9, a = u % 9;
            ws[G_OFF + u] = mat[(size_t)(i*72)*81 + a*9] * rs;
        }
        return;
    }
    int b = blockIdx.x - 1;
    __shared__ float sin_[243];
    __shared__ float cm[27];
    __shared__ float cat[5184];
    __shared__ float z1[108];
    __shared__ float z2[24];
    __shared__ float v1[24];
    __shared__ float v2[12];

    const float BN  = 1.0f / sqrtf(1.001f);
    const float BN2 = BN * BN;

    for (int u = t; u < 243; u += 256) sin_[u] = inp[b*243 + u];
    __syncthreads();

    // w branch (t<81), colmax (81..107), d1 conv (128..235)
    if (t < 81) {
        float s = w1_b[0];
        for (int i = 0; i < 3; ++i) s += sin_[t*3+i] * w1_k[i];
        ws[WB_OFF + b*81 + t] = LEAKY(s);
    } else if (t < 108) {
        int u = t - 81;                       // c*3+ch
        float m = 0.f;
        for (int r = 0; r < 9; ++r) m = fmaxf(m, fabsf(sin_[r*27 + u]));
        cm[u] = 0.001f + m;
    }
    if (t >= 128 && t < 236) {
        int u = t - 128;                      // oy*36 + ox*12 + o
        int o = u % 12, ox = (u/12) % 3, oy = u/36;
        float s = 0.f;
        for (int kh = 0; kh < 5; ++kh) {
            int iy = oy*3 - 1 + kh;
            if (iy < 0 || iy > 8) continue;
            for (int kw = 0; kw < 5; ++kw) {
                int ix = ox*3 - 1 + kw;
                if (ix < 0 || ix > 8) continue;
                for (int i = 0; i < 3; ++i)
                    s += sin_[(iy*9+ix)*3 + i] * d1_k[((kh*5+kw)*3 + i)*12 + o];
            }
        }
        z1[u] = LEAKY(BN2 * s);
    }
    __syncthreads();

    // im = leaky(conv1x1(inp / colmax)) ; layout (b,ch,81)
    if (t < 243) {
        int o = t / 81, p = t % 81;
        int c = p % 9;
        float s = x1_b[o];
        for (int i = 0; i < 3; ++i)
            s += (sin_[p*3+i] / cm[c*3+i]) * x1_k[i*3 + o];
        ws[IM_OFF + (b*3 + o)*81 + p] = LEAKY(s);
    }
    __syncthreads();

    // d2 conv: 3x3x12 -> 1x1x24 (kernel rows/cols 1..3 valid)
    if (t < 24) {
        float s = 0.f;
        for (int kh = 1; kh < 4; ++kh)
            for (int kw = 1; kw < 4; ++kw)
                for (int i = 0; i < 12; ++i)
                    s += z1[((kh-1)*3 + (kw-1))*12 + i] * d2_k[((kh*5+kw)*12 + i)*24 + t];
        z2[t] = LEAKY(BN * s);
    }
    __syncthreads();
    if (t < 24) {
        float s = h1_b[t];
        for (int i = 0; i < 24; ++i) s += z2[i] * h1_w[i*24 + t];
        v1[t] = s;
    }
    __syncthreads();
    if (t < 12) {
        float s = h2_b[t];
        for (int i = 0; i < 24; ++i) s += v1[i] * h2_w[i*12 + t];
        v2[t] = s;
    }
    __syncthreads();
    if (t == 0) {
        float s = h3_b[0];
        for (int i = 0; i < 12; ++i) s += v2[i] * h3_w[i];
        ws[LAM_OFF + b] = 0.01f / (1.f + expf(-s));   // 0.1*sigmoid * 0.1
    }

    // y branch: cat = [y1(32) | y2(32)] per position
    for (int u = t; u < 5184; u += 256) {
        int pos = u / 64, i = u % 64;
        int r = pos / 9, c = pos % 9;
        float s;
        if (i < 32) {
            s = y17_b[i];
            for (int kw = 0; kw < 7; ++kw) {
                int cc = c - 3 + kw;
                if (cc < 0 || cc > 8) continue;
                for (int ii = 0; ii < 3; ++ii)
                    s += sin_[(r*9+cc)*3 + ii] * y17_k[(kw*3+ii)*32 + i];
            }
        } else {
            int i2 = i - 32;
            s = y71_b[i2];
            for (int kh = 0; kh < 7; ++kh) {
                int rr = r - 3 + kh;
                if (rr < 0 || rr > 8) continue;
                for (int ii = 0; ii < 3; ++ii)
                    s += sin_[(rr*9+c)*3 + ii] * y71_k[(kh*3+ii)*32 + i2];
            }
        }
        cat[pos*64 + i] = s;
    }
    __syncthreads();
    for (int u = t; u < 2592; u += 256) {
        int pos = u / 32, o = u % 32;
        float s = yc_b[o];
        for (int i = 0; i < 64; ++i) s += cat[pos*64 + i] * yc_k[i*32 + o];
        ws[YBR_OFF + (b*81 + pos)*32 + o] = LEAKY(s);
    }
}

// ======================= FISTA (unchanged from R8, hardware-verified) =======
// 576 threads = 9 waves. t = j*8 + gg: lane owns rows i = 8*s + gg (s=0..8)
// of column j = 8*w + rr. Toeplitz band on both row and column sides.
// 2 barriers/iter; VGPR 52, no spill; 152.9us measured.

#define DPP_XOR1 0xB1   // quad_perm {1,0,3,2}
#define DPP_XOR2 0x4E   // quad_perm {2,3,0,1}
#define DPP_HM   0x141  // row_half_mirror (cross-quad within 8; quads uniform)
#define DPP_ROR8 0x128  // row_ror:8 == lane xor 8 within 16-lane row

template<int CTRL>
__device__ __forceinline__ float dppadd(float v) {
    return v + __int_as_float(__builtin_amdgcn_update_dpp(
        0, __float_as_int(v), CTRL, 0xF, 0xF, true));
}

#define STEPMID(s,sm,sp) { \
    float re = gm*q##sm + g0*q##s + gp*q##sp; \
    float wv = Yv##s + re; \
    float cl = fminf(fmaxf(wv, -lam), lam); \
    float yn = wv - cl; \
    float yx = yn + cmom*(yn - Yl##s); \
    Yl##s = yn; Yv##s = yx; \
    u##sm += yx*gm; u##s += yx*g0; u##sp += yx*gp; }
#define STEP0 { \
    float re = g0*q0 + gp*q1; \
    float wv = Yv0 + re; \
    float cl = fminf(fmaxf(wv, -lam), lam); \
    float yn = wv - cl; \
    float yx = yn + cmom*(yn - Yl0); \
    Yl0 = yn; Yv0 = yx; \
    u0 += yx*g0; u1 += yx*gp; }
#define STEP8 { \
    float re = gm*q7 + g0*q8; \
    float wv = Yv8 + re; \
    float cl = fminf(fmaxf(wv, -lam), lam); \
    float yn = wv - cl; \
    float yx = yn + cmom*(yn - Yl8); \
    Yl8 = yn; Yv8 = yx; \
    u7 += yx*gm; u8 += yx*g0; }

#define TSP(a) { float v = u##a; \
    v = dppadd<DPP_XOR1>(v); v = dppadd<DPP_XOR2>(v); v = dppadd<DPP_HM>(v); \
    float vA = v*Gjg, vB = v*Gj8; \
    spA_##a = dppadd<DPP_ROR8>(vA); spB_##a = dppadd<DPP_ROR8>(vB); }

#define QT3(a) float q##a = cmc*rm_##a + c0c*r0_##a + cpc*rp_##a;

#define OUTW(s) cs_out[(size_t)(b*5184 + (8*s+gg)*72 + j)*3 + ch] = Yl##s;

__global__ __launch_bounds__(576, 3) void fista_kernel(
    const float* __restrict__ ws, float* __restrict__ cs_out)
{
    __shared__ __align__(16) float SPm[36*108];  // 36 sets x (9 slots x 12 pad)
    __shared__ __align__(16) float Rm[108];      // R[b][a], rows of 12

    int t = threadIdx.x;
    int b = blockIdx.x / 3, ch = blockIdx.x % 3;
    const float* g = ws + G_OFF;
    float lam = ws[LAM_OFF + b];

    int j = t >> 3, gg = t & 7;      // column j, row-group gg (i = 8s+gg)
    int l = t & 63;                  // lane in wave
    int w = t >> 6;                  // wave index = j>>3
    int rr = j & 7;                  // j = 8w + rr

    // ---- row-side Toeplitz G registers ----
    float gm = g[(gg + 8)*9 + 0];    // f(gg+8)
    float g0 = g[gg*9 + 0];          // f(gg)
    float gp = g[gg*9 + 1];          // f(gg-8)

    // ---- column-side Toeplitz coeffs (qt and S band) ----
    float cmc = (w > 0) ? g[(rr + 8)*9 + 0] : 0.f;   // f(rr+8), b=w-1
    float c0c = g[rr*9 + 0];                          // f(rr),   b=w
    float cpc = (w < 8) ? g[rr*9 + 1] : 0.f;          // f(rr-8), b=w+1
    int bmr = (w > 0) ? w - 1 : 0;   // clamped row indices (coeff is 0 there)
    int bpr = (w < 8) ? w + 1 : 8;

    float Gjg = g[j*9 + gg];         // g[j][gg]  (TSP store side)
    float Gj8 = g[j*9 + 8];          // g[j][8]

    // reducer role (t < 324): ab = a*9+b pair, pp = row-set split (4 rows)
    int ab = t >> 2, pp = t & 3;
    int aa = ab / 9, bb = ab % 9;
    float im_ab = (t < 324) ? ws[IM_OFF + (b*3 + ch)*81 + ab] : 0.f;

    // init R = im (transposed: Rm[b][a] = im[a][b])
    if (t < 81) {
        Rm[(t % 9)*12 + (t / 9)] = ws[IM_OFF + (b*3 + ch)*81 + t];
    }

    float Yv0=0,Yv1=0,Yv2=0,Yv3=0,Yv4=0,Yv5=0,Yv6=0,Yv7=0,Yv8=0;
    float Yl0=0,Yl1=0,Yl2=0,Yl3=0,Yl4=0,Yl5=0,Yl6=0,Yl7=0,Yl8=0;
    float tk = 1.f;
    __syncthreads();

    for (int it = 0; it < 100; ++it) {
        float tn = 0.5f*(1.f + sqrtf(1.f + 4.f*tk*tk));
        float cmom = (tk - 1.f) / tn;
        tk = tn;

        // ---- qt[a]: 3-term band over broadcast R rows
        float4 mv0 = *(const float4*)(Rm + bmr*12);
        float4 mv1 = *(const float4*)(Rm + bmr*12 + 4);
        float  mv2 = Rm[bmr*12 + 8];
        float rm_0=mv0.x, rm_1=mv0.y, rm_2=mv0.z, rm_3=mv0.w,
              rm_4=mv1.x, rm_5=mv1.y, rm_6=mv1.z, rm_7=mv1.w, rm_8=mv2;
        float4 zv0 = *(const float4*)(Rm + w*12);
        float4 zv1 = *(const float4*)(Rm + w*12 + 4);
        float  zv2 = Rm[w*12 + 8];
        float r0_0=zv0.x, r0_1=zv0.y, r0_2=zv0.z, r0_3=zv0.w,
              r0_4=zv1.x, r0_5=zv1.y, r0_6=zv1.z, r0_7=zv1.w, r0_8=zv2;
        float4 pv0 = *(const float4*)(Rm + bpr*12);
        float4 pv1 = *(const float4*)(Rm + bpr*12 + 4);
        float  pv2 = Rm[bpr*12 + 8];
        float rp_0=pv0.x, rp_1=pv0.y, rp_2=pv0.z, rp_3=pv0.w,
              rp_4=pv1.x, rp_5=pv1.y, rp_6=pv1.z, rp_7=pv1.w, rp_8=pv2;
        QT3(0) QT3(1) QT3(2) QT3(3) QT3(4) QT3(5) QT3(6) QT3(7) QT3(8)

        // ---- y-update for 9 owned rows + u partials (3-term band)
        float u0=0,u1=0,u2=0,u3=0,u4=0,u5=0,u6=0,u7=0,u8=0;
        STEP0
        STEPMID(1,0,2) STEPMID(2,1,3) STEPMID(3,2,4) STEPMID(4,3,5)
        STEPMID(5,4,6) STEPMID(6,5,7) STEPMID(7,6,8)
        STEP8
        if (it == 99) break;

        // ---- T butterfly + S partials (j-pair folded)
        float spA_0,spA_1,spA_2,spA_3,spA_4,spA_5,spA_6,spA_7,spA_8;
        float spB_0,spB_1,spB_2,spB_3,spB_4,spB_5,spB_6,spB_7,spB_8;
        TSP(0) TSP(1) TSP(2) TSP(3) TSP(4) TSP(5) TSP(6) TSP(7) TSP(8)

        // ---- store partial sets: set = wave*4 + row; slot gg (and slot 8)
        int setb = ((t >> 6)*4 + (l >> 4))*108;
        if ((l & 8) == 0) {
            float* d = &SPm[setb + gg*12];
            ((float4*)d)[0] = make_float4(spA_0,spA_1,spA_2,spA_3);
            ((float4*)d)[1] = make_float4(spA_4,spA_5,spA_6,spA_7);
            d[8] = spA_8;
            if (gg == 0) {
                float* d2 = &SPm[setb + 96];
                ((float4*)d2)[0] = make_float4(spB_0,spB_1,spB_2,spB_3);
                ((float4*)d2)[1] = make_float4(spB_4,spB_5,spB_6,spB_7);
                d2[8] = spB_8;
            }
        }
        __syncthreads();

        // ---- reduce: only waves {bb-1, bb, bb+1} contribute to S[.][bb]
        if (t < 324) {
            float s = SPm[(bb*4 + pp)*108 + bb*12 + aa];
            if (bb > 0) s += SPm[((bb-1)*4 + pp)*108 + bb*12 + aa];
            if (bb < 8) s += SPm[((bb+1)*4 + pp)*108 + bb*12 + aa];
            s = dppadd<DPP_XOR1>(s);
            s = dppadd<DPP_XOR2>(s);
            if (pp == 0) Rm[bb*12 + aa] = im_ab - s;
        }
        __syncthreads();
    }

    // ---- output: rows 8s+gg of column j
    OUTW(0) OUTW(1) OUTW(2) OUTW(3) OUTW(4) OUTW(5) OUTW(6) OUTW(7) OUTW(8)
}

// ======================= fused c51 + c15, ROW-SPLIT =======================
// R9's per-batch fusion collapsed parallelism (32 blocks, 0.6% occupancy,
// 162us). The c15 conv (1x5, stride 2) reads exactly ONE x1 row (iy = 2*oy)
// per x2 row, so fuse at row granularity: block = (b, oy) -> 576 blocks.
// Stage 1: x1 row 2*oy (36x16 = 576 floats, 2.3KB LDS) from cs rows
// 4*oy-1 .. 4*oy+3. Stage 2: x2 row oy (18x32) -> global. Same arithmetic
// and layouts as the separate kernels (hardware-verified in R8).
__global__ __launch_bounds__(256) void c51c15_kernel(
    const float* __restrict__ cs, const float* __restrict__ k51,
    const float* __restrict__ b51, const float* __restrict__ k15,
    const float* __restrict__ b15, float* __restrict__ x2out)
{
    __shared__ float x1s[36*16];      // one x1 row
    int t = threadIdx.x;
    int b = blockIdx.x / 18, oy = blockIdx.x % 18;

    // stage 1: x1 row iy1 = 2*oy; input cs rows 4*oy-1+kh
    for (int u = t; u < 36*16; u += 256) {
        int o = u & 15, ox = u >> 4;
        float s = b51[o];
        int ix = ox*2;
        for (int kh = 0; kh < 5; ++kh) {
            int iy = oy*4 - 1 + kh;
            if (iy < 0 || iy >= 72) continue;
            const float* p = cs + ((size_t)(b*72 + iy)*72 + ix)*3;
            const float* kk = k51 + kh*48 + o;
            s += p[0]*kk[0] + p[1]*kk[16] + p[2]*kk[32];
        }
        x1s[u] = s;
    }
    __syncthreads();

    // stage 2: x2 row oy (18 ox x 32 o)
    for (int u = t; u < 18*32; u += 256) {
        int o = u & 31, ox = u >> 5;
        float s = b15[o];
        for (int kw = 0; kw < 5; ++kw) {
            int ix = ox*2 - 1 + kw;
            if (ix < 0 || ix >= 36) continue;
            const float* p = x1s + ix*16;
            const float* kk = k15 + kw*512 + o;
            for (int i = 0; i < 16; ++i) s += p[i]*kk[i*32];
        }
        x2out[((size_t)(b*18 + oy)*18 + ox)*32 + o] = s;
    }
}

// ======================= fused c55 + x2conv + out =======================
// Block = 256 threads = 4 positions x 64 channels; grid = 2592/4 = 648.
// Phase 1: x3[pos][o] (c55) into LDS. Phase 2: the 41 output channels per
// position: q=0 w-branch copy, q=1..8 leaky(1x1 conv of x3), q>=9 y-branch
// copy. x3 never touches HBM. (Verified R9: passed, not in slow top-5.)
__global__ __launch_bounds__(256) void c55out_kernel(
    const float* __restrict__ x2g, const float* __restrict__ k55,
    const float* __restrict__ b55, const float* __restrict__ ws,
    const float* __restrict__ x2_k, const float* __restrict__ x2_b,
    float* __restrict__ out)
{
    __shared__ float x3s[4][64];
    int t = threadIdx.x;
    int lp = t >> 6;                      // local position 0..3
    int o  = t & 63;
    int pg = blockIdx.x*4 + lp;           // global position
    int b  = pg / 81, rc = pg % 81;
    int r  = rc / 9,  c  = rc % 9;

    // phase 1: c55 at (b, r, c) channel o
    {
        float s = b55[o];
        for (int kh = 0; kh < 5; ++kh) {
            int iy = r*2 - 1 + kh;
            if (iy < 0 || iy >= 18) continue;
            for (int kw = 0; kw < 5; ++kw) {
                int ix = c*2 - 1 + kw;
                if (ix < 0 || ix >= 18) continue;
                const float* p = x2g + ((size_t)(b*18 + iy)*18 + ix)*32;
                const float* kk = k55 + (kh*5+kw)*2048 + o;
                for (int i = 0; i < 32; ++i) s += p[i]*kk[i*64];
            }
        }
        x3s[lp][o] = s;
    }
    __syncthreads();

    // phase 2: 41 outputs per position (164 active threads)
    if (t < 4*41) {
        int lp2 = t / 41, q = t % 41;
        int pg2 = blockIdx.x*4 + lp2;
        int b2  = pg2 / 81, rc2 = pg2 % 81;
        float val;
        if (q == 0) {
            val = ws[WB_OFF + b2*81 + rc2];
        } else if (q <= 8) {
            int o2 = q - 1;
            float s = x2_b[o2];
            for (int i = 0; i < 64; ++i) s += x3s[lp2][i]*x2_k[i*8 + o2];
            val = LEAKY(s);
        } else {
            val = ws[YBR_OFF + (size_t)(b2*81 + rc2)*32 + (q - 9)];
        }
        out[(size_t)pg2*41 + q] = val;
    }
}

// ======================= launch =======================
extern "C" void kernel_launch(void* const* d_in, const int* in_sizes, int n_in,
                              void* d_out, int out_size, void* d_ws, size_t ws_size,
                              hipStream_t stream) {
    const float* inp   = (const float*)d_in[0];
    const float* mat   = (const float*)d_in[1];
    const float* w1_k  = (const float*)d_in[2];
    const float* w1_b  = (const float*)d_in[3];
    const float* x1_k  = (const float*)d_in[4];
    const float* x1_b  = (const float*)d_in[5];
    const float* c51_k = (const float*)d_in[6];
    const float* c51_b = (const float*)d_in[7];
    const float* c15_k = (const float*)d_in[8];
    const float* c15_b = (const float*)d_in[9];
    const float* c55_k = (const float*)d_in[10];
    const float* c55_b = (const float*)d_in[11];
    const float* x2_k  = (const float*)d_in[12];
    const float* x2_b  = (const float*)d_in[13];
    const float* y17_k = (const float*)d_in[14];
    const float* y17_b = (const float*)d_in[15];
    const float* y71_k = (const float*)d_in[16];
    const float* y71_b = (const float*)d_in[17];
    const float* yc_k  = (const float*)d_in[18];
    const float* yc_b  = (const float*)d_in[19];
    const float* d1_k  = (const float*)d_in[20];
    const float* d2_k  = (const float*)d_in[21];
    const float* h1_w  = (const float*)d_in[22];
    const float* h1_b  = (const float*)d_in[23];
    const float* h2_w  = (const float*)d_in[24];
    const float* h2_b  = (const float*)d_in[25];
    const float* h3_w  = (const float*)d_in[26];
    const float* h3_b  = (const float*)d_in[27];

    float* ws  = (float*)d_ws;
    float* out = (float*)d_out;
    float* cs  = out + OUT0;

    hipLaunchKernelGGL(prep_kernel, dim3(33), dim3(256), 0, stream,
        inp, mat, w1_k, w1_b, x1_k, x1_b, y17_k, y17_b, y71_k, y71_b,
        yc_k, yc_b, d1_k, d2_k, h1_w, h1_b, h2_w, h2_b, h3_w, h3_b, ws);
    hipLaunchKernelGGL(fista_kernel, dim3(96), dim3(576), 0, stream, ws, cs);
    hipLaunchKernelGGL(c51c15_kernel, dim3(576), dim3(256), 0, stream,
        cs, c51_k, c51_b, c15_k, c15_b, ws + X2_OFF);
    hipLaunchKernelGGL(c55out_kernel, dim3(648), dim3(256), 0, stream,
        ws + X2_OFF, c55_k, c55_b, ws, x2_k, x2_b, out);
}

// Round 11
// 338.655 us; speedup vs baseline: 1.1367x; 1.0238x over previous
//
#include <hip/hip_runtime.h>
#include <math.h>

#define LEAKY(x) ((x) >= 0.f ? (x) : 0.3f*(x))

// ---- workspace float offsets ----
#define G_OFF   0         // 648     extracted g~ (72x9)
#define IM_OFF  648       // 7776    im (b,ch,81)
#define LAM_OFF 8424      // 32      lambda per batch
#define WB_OFF  8456      // 2592    w branch (b,81)
#define YBR_OFF 11048     // 82944   y branch (b,81,32)
#define X2_OFF  757544    // 331776  conv15 out (b,18,18,32)

#define OUT0 106272       // elements in output 0; cs_out follows

// ======================= prep =======================
__global__ __launch_bounds__(256) void prep_kernel(
    const float* __restrict__ inp, const float* __restrict__ mat,
    const float* __restrict__ w1_k, const float* __restrict__ w1_b,
    const float* __restrict__ x1_k, const float* __restrict__ x1_b,
    const float* __restrict__ y17_k, const float* __restrict__ y17_b,
    const float* __restrict__ y71_k, const float* __restrict__ y71_b,
    const float* __restrict__ yc_k, const float* __restrict__ yc_b,
    const float* __restrict__ d1_k, const float* __restrict__ d2_k,
    const float* __restrict__ h1_w, const float* __restrict__ h1_b,
    const float* __restrict__ h2_w, const float* __restrict__ h2_b,
    const float* __restrict__ h3_w, const float* __restrict__ h3_b,
    float* __restrict__ ws)
{
    int t = threadIdx.x;
    if (blockIdx.x == 0) {
        // extract separable factor: g[i][a] = mat[i*72, a*9] / sqrt(mat[0,0])
        float rs = rsqrtf(mat[0]);
        for (int u = t; u < 648; u += 256) {
            int i = u / 9, a = u % 9;
            ws[G_OFF + u] = mat[(size_t)(i*72)*81 + a*9] * rs;
        }
        return;
    }
    int b = blockIdx.x - 1;
    __shared__ float sin_[243];
    __shared__ float cm[27];
    __shared__ float cat[5184];
    __shared__ float z1[108];
    __shared__ float z2[24];
    __shared__ float v1[24];
    __shared__ float v2[12];

    const float BN  = 1.0f / sqrtf(1.001f);
    const float BN2 = BN * BN;

    for (int u = t; u < 243; u += 256) sin_[u] = inp[b*243 + u];
    __syncthreads();

    // w branch (t<81), colmax (81..107), d1 conv (128..235)
    if (t < 81) {
        float s = w1_b[0];
        for (int i = 0; i < 3; ++i) s += sin_[t*3+i] * w1_k[i];
        ws[WB_OFF + b*81 + t] = LEAKY(s);
    } else if (t < 108) {
        int u = t - 81;                       // c*3+ch
        float m = 0.f;
        for (int r = 0; r < 9; ++r) m = fmaxf(m, fabsf(sin_[r*27 + u]));
        cm[u] = 0.001f + m;
    }
    if (t >= 128 && t < 236) {
        int u = t - 128;                      // oy*36 + ox*12 + o
        int o = u % 12, ox = (u/12) % 3, oy = u/36;
        float s = 0.f;
        for (int kh = 0; kh < 5; ++kh) {
            int iy = oy*3 - 1 + kh;
            if (iy < 0 || iy > 8) continue;
            for (int kw = 0; kw < 5; ++kw) {
                int ix = ox*3 - 1 + kw;
                if (ix < 0 || ix > 8) continue;
                for (int i = 0; i < 3; ++i)
                    s += sin_[(iy*9+ix)*3 + i] * d1_k[((kh*5+kw)*3 + i)*12 + o];
            }
        }
        z1[u] = LEAKY(BN2 * s);
    }
    __syncthreads();

    // im = leaky(conv1x1(inp / colmax)) ; layout (b,ch,81)
    if (t < 243) {
        int o = t / 81, p = t % 81;
        int c = p % 9;
        float s = x1_b[o];
        for (int i = 0; i < 3; ++i)
            s += (sin_[p*3+i] / cm[c*3+i]) * x1_k[i*3 + o];
        ws[IM_OFF + (b*3 + o)*81 + p] = LEAKY(s);
    }
    __syncthreads();

    // d2 conv: 3x3x12 -> 1x1x24 (kernel rows/cols 1..3 valid)
    if (t < 24) {
        float s = 0.f;
        for (int kh = 1; kh < 4; ++kh)
            for (int kw = 1; kw < 4; ++kw)
                for (int i = 0; i < 12; ++i)
                    s += z1[((kh-1)*3 + (kw-1))*12 + i] * d2_k[((kh*5+kw)*12 + i)*24 + t];
        z2[t] = LEAKY(BN * s);
    }
    __syncthreads();
    if (t < 24) {
        float s = h1_b[t];
        for (int i = 0; i < 24; ++i) s += z2[i] * h1_w[i*24 + t];
        v1[t] = s;
    }
    __syncthreads();
    if (t < 12) {
        float s = h2_b[t];
        for (int i = 0; i < 24; ++i) s += v1[i] * h2_w[i*12 + t];
        v2[t] = s;
    }
    __syncthreads();
    if (t == 0) {
        float s = h3_b[0];
        for (int i = 0; i < 12; ++i) s += v2[i] * h3_w[i];
        ws[LAM_OFF + b] = 0.01f / (1.f + expf(-s));   // 0.1*sigmoid * 0.1
    }

    // y branch: cat = [y1(32) | y2(32)] per position
    for (int u = t; u < 5184; u += 256) {
        int pos = u / 64, i = u % 64;
        int r = pos / 9, c = pos % 9;
        float s;
        if (i < 32) {
            s = y17_b[i];
            for (int kw = 0; kw < 7; ++kw) {
                int cc = c - 3 + kw;
                if (cc < 0 || cc > 8) continue;
                for (int ii = 0; ii < 3; ++ii)
                    s += sin_[(r*9+cc)*3 + ii] * y17_k[(kw*3+ii)*32 + i];
            }
        } else {
            int i2 = i - 32;
            s = y71_b[i2];
            for (int kh = 0; kh < 7; ++kh) {
                int rr = r - 3 + kh;
                if (rr < 0 || rr > 8) continue;
                for (int ii = 0; ii < 3; ++ii)
                    s += sin_[(rr*9+c)*3 + ii] * y71_k[(kh*3+ii)*32 + i2];
            }
        }
        cat[pos*64 + i] = s;
    }
    __syncthreads();
    for (int u = t; u < 2592; u += 256) {
        int pos = u / 32, o = u % 32;
        float s = yc_b[o];
        for (int i = 0; i < 64; ++i) s += cat[pos*64 + i] * yc_k[i*32 + o];
        ws[YBR_OFF + (b*81 + pos)*32 + o] = LEAKY(s);
    }
}

// ======================= FISTA =======================
// 576 threads = 9 waves. t = j*8 + gg: lane owns rows i = 8*s + gg (s=0..8)
// of column j = 8*w + rr. Toeplitz band on both row and column sides
// (R8 skeleton, hardware-verified: VGPR 52, 922K conflicts, 153us).
//
// NEW (this round): ONE barrier per iteration. The old reduce phase +
// barrier #2 are replaced by wave-private R: after the single barrier,
// each wave redundantly computes its 3 needed R rows {w-1, w, w+1}
// (column-Toeplitz band) from SPm into a private LDS strip Rpriv[w].
// Wave-private LDS write->read needs no barrier (lgkmcnt only, compiler-
// inserted). SPm is DOUBLE-BUFFERED on it&1: a wave may store iteration
// k+1's partials while a lagging wave still reads iteration k's; the
// barrier's implicit waitcnt makes the 2-deep rotation race-free
// (store buf(k+2) can only happen after barrier(k+1), which all waves
// reach only after completing their buf(k) reads).
// Per-wave R work: lanes 0..53, l = r3*18 + a*2 + half; each lane sums 6
// SPm terms (3 band waves x 2 pp), XOR1-fold with partner, half==0 writes
// R = im - S. Clipped rows (w=0/8) write 0 (their qt coeff is already 0).

#define DPP_XOR1 0xB1   // quad_perm {1,0,3,2}
#define DPP_XOR2 0x4E   // quad_perm {2,3,0,1}
#define DPP_HM   0x141  // row_half_mirror (cross-quad within 8; quads uniform)
#define DPP_ROR8 0x128  // row_ror:8 == lane xor 8 within 16-lane row

#define SPHALF 3888     // 36 sets x 108

template<int CTRL>
__device__ __forceinline__ float dppadd(float v) {
    return v + __int_as_float(__builtin_amdgcn_update_dpp(
        0, __float_as_int(v), CTRL, 0xF, 0xF, true));
}

#define STEPMID(s,sm,sp) { \
    float re = gm*q##sm + g0*q##s + gp*q##sp; \
    float wv = Yv##s + re; \
    float cl = fminf(fmaxf(wv, -lam), lam); \
    float yn = wv - cl; \
    float yx = yn + cmom*(yn - Yl##s); \
    Yl##s = yn; Yv##s = yx; \
    u##sm += yx*gm; u##s += yx*g0; u##sp += yx*gp; }
#define STEP0 { \
    float re = g0*q0 + gp*q1; \
    float wv = Yv0 + re; \
    float cl = fminf(fmaxf(wv, -lam), lam); \
    float yn = wv - cl; \
    float yx = yn + cmom*(yn - Yl0); \
    Yl0 = yn; Yv0 = yx; \
    u0 += yx*g0; u1 += yx*gp; }
#define STEP8 { \
    float re = gm*q7 + g0*q8; \
    float wv = Yv8 + re; \
    float cl = fminf(fmaxf(wv, -lam), lam); \
    float yn = wv - cl; \
    float yx = yn + cmom*(yn - Yl8); \
    Yl8 = yn; Yv8 = yx; \
    u7 += yx*gm; u8 += yx*g0; }

#define TSP(a) { float v = u##a; \
    v = dppadd<DPP_XOR1>(v); v = dppadd<DPP_XOR2>(v); v = dppadd<DPP_HM>(v); \
    float vA = v*Gjg, vB = v*Gj8; \
    spA_##a = dppadd<DPP_ROR8>(vA); spB_##a = dppadd<DPP_ROR8>(vB); }

#define QT3(a) float q##a = cmc*rm_##a + c0c*r0_##a + cpc*rp_##a;

#define OUTW(s) cs_out[(size_t)(b*5184 + (8*s+gg)*72 + j)*3 + ch] = Yl##s;

__global__ __launch_bounds__(576, 3) void fista_kernel(
    const float* __restrict__ ws, float* __restrict__ cs_out)
{
    __shared__ __align__(16) float SPm[2*SPHALF];  // double-buffered partial sets
    __shared__ __align__(16) float Rpriv[9*36];    // per-wave rows {w-1,w,w+1} x 12

    int t = threadIdx.x;
    int b = blockIdx.x / 3, ch = blockIdx.x % 3;
    const float* g = ws + G_OFF;
    float lam = ws[LAM_OFF + b];

    int j = t >> 3, gg = t & 7;      // column j, row-group gg (i = 8s+gg)
    int l = t & 63;                  // lane in wave
    int w = t >> 6;                  // wave index = j>>3
    int rr = j & 7;                  // j = 8w + rr

    // ---- row-side Toeplitz G registers ----
    float gm = g[(gg + 8)*9 + 0];    // f(gg+8)
    float g0 = g[gg*9 + 0];          // f(gg)
    float gp = g[gg*9 + 1];          // f(gg-8)

    // ---- column-side Toeplitz coeffs (qt band) ----
    float cmc = (w > 0) ? g[(rr + 8)*9 + 0] : 0.f;   // f(rr+8), b=w-1
    float c0c = g[rr*9 + 0];                          // f(rr),   b=w
    float cpc = (w < 8) ? g[rr*9 + 1] : 0.f;          // f(rr-8), b=w+1

    float Gjg = g[j*9 + gg];         // g[j][gg]  (TSP store side)
    float Gj8 = g[j*9 + 8];          // g[j][8]

    // ---- R-compute role (lanes 0..53 of each wave) ----
    int r3 = l / 18, rrem = l % 18, ra = rrem >> 1, rh = rrem & 1;
    bool ract = (l < 54);
    int rb = w - 1 + r3;                       // target R row b
    bool rbval = ract && (rb >= 0) && (rb <= 8);
    int rbc = rb < 0 ? 0 : (rb > 8 ? 8 : rb);  // clamped for addressing
    int slotc = rbc*12 + ra;
    int wmv = rbc > 0 ? rbc - 1 : 0;           // band waves (clamped + masked)
    int wpv = rbc < 8 ? rbc + 1 : 8;
    float mmsk = (rbc > 0) ? 1.f : 0.f;
    float mpsk = (rbc < 8) ? 1.f : 0.f;
    int p0 = rh*2;                             // this lane's pp pair {p0, p0+1}
    float im_reg = rbval ? ws[IM_OFF + (b*3 + ch)*81 + ra*9 + rb] : 0.f;

    // init private R = im (wave-private: no barrier needed)
    if (ract && rh == 0) Rpriv[w*36 + r3*12 + ra] = rbval ? im_reg : 0.f;

    float Yv0=0,Yv1=0,Yv2=0,Yv3=0,Yv4=0,Yv5=0,Yv6=0,Yv7=0,Yv8=0;
    float Yl0=0,Yl1=0,Yl2=0,Yl3=0,Yl4=0,Yl5=0,Yl6=0,Yl7=0,Yl8=0;
    float tk = 1.f;

    for (int it = 0; it < 100; ++it) {
        float tn = 0.5f*(1.f + sqrtf(1.f + 4.f*tk*tk));
        float cmom = (tk - 1.f) / tn;
        tk = tn;

        // ---- qt[a]: 3-term band over this wave's private R rows
        const float* Rw = Rpriv + w*36;
        float4 mv0 = *(const float4*)(Rw);
        float4 mv1 = *(const float4*)(Rw + 4);
        float  mv2 = Rw[8];
        float rm_0=mv0.x, rm_1=mv0.y, rm_2=mv0.z, rm_3=mv0.w,
              rm_4=mv1.x, rm_5=mv1.y, rm_6=mv1.z, rm_7=mv1.w, rm_8=mv2;
        float4 zv0 = *(const float4*)(Rw + 12);
        float4 zv1 = *(const float4*)(Rw + 16);
        float  zv2 = Rw[20];
        float r0_0=zv0.x, r0_1=zv0.y, r0_2=zv0.z, r0_3=zv0.w,
              r0_4=zv1.x, r0_5=zv1.y, r0_6=zv1.z, r0_7=zv1.w, r0_8=zv2;
        float4 pv0 = *(const float4*)(Rw + 24);
        float4 pv1 = *(const float4*)(Rw + 28);
        float  pv2 = Rw[32];
        float rp_0=pv0.x, rp_1=pv0.y, rp_2=pv0.z, rp_3=pv0.w,
              rp_4=pv1.x, rp_5=pv1.y, rp_6=pv1.z, rp_7=pv1.w, rp_8=pv2;
        QT3(0) QT3(1) QT3(2) QT3(3) QT3(4) QT3(5) QT3(6) QT3(7) QT3(8)

        // ---- y-update for 9 owned rows + u partials (3-term band)
        float u0=0,u1=0,u2=0,u3=0,u4=0,u5=0,u6=0,u7=0,u8=0;
        STEP0
        STEPMID(1,0,2) STEPMID(2,1,3) STEPMID(3,2,4) STEPMID(4,3,5)
        STEPMID(5,4,6) STEPMID(6,5,7) STEPMID(7,6,8)
        STEP8
        if (it == 99) break;

        // ---- T butterfly + S partials (j-pair folded)
        float spA_0,spA_1,spA_2,spA_3,spA_4,spA_5,spA_6,spA_7,spA_8;
        float spB_0,spB_1,spB_2,spB_3,spB_4,spB_5,spB_6,spB_7,spB_8;
        TSP(0) TSP(1) TSP(2) TSP(3) TSP(4) TSP(5) TSP(6) TSP(7) TSP(8)

        // ---- store partial sets into parity buffer
        float* SP = SPm + (it & 1)*SPHALF;
        int setb = (w*4 + (l >> 4))*108;
        if ((l & 8) == 0) {
            float* d = SP + setb + gg*12;
            ((float4*)d)[0] = make_float4(spA_0,spA_1,spA_2,spA_3);
            ((float4*)d)[1] = make_float4(spA_4,spA_5,spA_6,spA_7);
            d[8] = spA_8;
            if (gg == 0) {
                float* d2 = SP + setb + 96;
                ((float4*)d2)[0] = make_float4(spB_0,spB_1,spB_2,spB_3);
                ((float4*)d2)[1] = make_float4(spB_4,spB_5,spB_6,spB_7);
                d2[8] = spB_8;
            }
        }
        __syncthreads();   // the ONLY barrier in the loop

        // ---- per-wave private R rows from SPm band
        if (ract) {
            const float* S = SPm + (it & 1)*SPHALF;
            float s = S[(rbc*4 + p0)*108 + slotc] + S[(rbc*4 + p0+1)*108 + slotc]
               + mmsk*(S[(wmv*4 + p0)*108 + slotc] + S[(wmv*4 + p0+1)*108 + slotc])
               + mpsk*(S[(wpv*4 + p0)*108 + slotc] + S[(wpv*4 + p0+1)*108 + slotc]);
            s = dppadd<DPP_XOR1>(s);
            if (rh == 0)
                Rpriv[w*36 + r3*12 + ra] = rbval ? (im_reg - s) : 0.f;
        }
    }

    // ---- output: rows 8s+gg of column j
    OUTW(0) OUTW(1) OUTW(2) OUTW(3) OUTW(4) OUTW(5) OUTW(6) OUTW(7) OUTW(8)
}

// ======================= fused c51 + c15, ROW-SPLIT =======================
// Block = (b, oy) -> 576 blocks; x1 row (2.3KB LDS) computed and consumed
// in-block. Hardware-verified R10 (steady-state not in slow top-5).
__global__ __launch_bounds__(256) void c51c15_kernel(
    const float* __restrict__ cs, const float* __restrict__ k51,
    const float* __restrict__ b51, const float* __restrict__ k15,
    const float* __restrict__ b15, float* __restrict__ x2out)
{
    __shared__ float x1s[36*16];      // one x1 row
    int t = threadIdx.x;
    int b = blockIdx.x / 18, oy = blockIdx.x % 18;

    // stage 1: x1 row iy1 = 2*oy; input cs rows 4*oy-1+kh
    for (int u = t; u < 36*16; u += 256) {
        int o = u & 15, ox = u >> 4;
        float s = b51[o];
        int ix = ox*2;
        for (int kh = 0; kh < 5; ++kh) {
            int iy = oy*4 - 1 + kh;
            if (iy < 0 || iy >= 72) continue;
            const float* p = cs + ((size_t)(b*72 + iy)*72 + ix)*3;
            const float* kk = k51 + kh*48 + o;
            s += p[0]*kk[0] + p[1]*kk[16] + p[2]*kk[32];
        }
        x1s[u] = s;
    }
    __syncthreads();

    // stage 2: x2 row oy (18 ox x 32 o)
    for (int u = t; u < 18*32; u += 256) {
        int o = u & 31, ox = u >> 5;
        float s = b15[o];
        for (int kw = 0; kw < 5; ++kw) {
            int ix = ox*2 - 1 + kw;
            if (ix < 0 || ix >= 36) continue;
            const float* p = x1s + ix*16;
            const float* kk = k15 + kw*512 + o;
            for (int i = 0; i < 16; ++i) s += p[i]*kk[i*32];
        }
        x2out[((size_t)(b*18 + oy)*18 + ox)*32 + o] = s;
    }
}

// ======================= fused c55 + x2conv + out =======================
// Block = 256 threads = 4 positions x 64 channels; grid = 648.
// Hardware-verified R9/R10.
__global__ __launch_bounds__(256) void c55out_kernel(
    const float* __restrict__ x2g, const float* __restrict__ k55,
    const float* __restrict__ b55, const float* __restrict__ ws,
    const float* __restrict__ x2_k, const float* __restrict__ x2_b,
    float* __restrict__ out)
{
    __shared__ float x3s[4][64];
    int t = threadIdx.x;
    int lp = t >> 6;                      // local position 0..3
    int o  = t & 63;
    int pg = blockIdx.x*4 + lp;           // global position
    int b  = pg / 81, rc = pg % 81;
    int r  = rc / 9,  c  = rc % 9;

    // phase 1: c55 at (b, r, c) channel o
    {
        float s = b55[o];
        for (int kh = 0; kh < 5; ++kh) {
            int iy = r*2 - 1 + kh;
            if (iy < 0 || iy >= 18) continue;
            for (int kw = 0; kw < 5; ++kw) {
                int ix = c*2 - 1 + kw;
                if (ix < 0 || ix >= 18) continue;
                const float* p = x2g + ((size_t)(b*18 + iy)*18 + ix)*32;
                const float* kk = k55 + (kh*5+kw)*2048 + o;
                for (int i = 0; i < 32; ++i) s += p[i]*kk[i*64];
            }
        }
        x3s[lp][o] = s;
    }
    __syncthreads();

    // phase 2: 41 outputs per position (164 active threads)
    if (t < 4*41) {
        int lp2 = t / 41, q = t % 41;
        int pg2 = blockIdx.x*4 + lp2;
        int b2  = pg2 / 81, rc2 = pg2 % 81;
        float val;
        if (q == 0) {
            val = ws[WB_OFF + b2*81 + rc2];
        } else if (q <= 8) {
            int o2 = q - 1;
            float s = x2_b[o2];
            for (int i = 0; i < 64; ++i) s += x3s[lp2][i]*x2_k[i*8 + o2];
            val = LEAKY(s);
        } else {
            val = ws[YBR_OFF + (size_t)(b2*81 + rc2)*32 + (q - 9)];
        }
        out[(size_t)pg2*41 + q] = val;
    }
}

// ======================= launch =======================
extern "C" void kernel_launch(void* const* d_in, const int* in_sizes, int n_in,
                              void* d_out, int out_size, void* d_ws, size_t ws_size,
                              hipStream_t stream) {
    const float* inp   = (const float*)d_in[0];
    const float* mat   = (const float*)d_in[1];
    const float* w1_k  = (const float*)d_in[2];
    const float* w1_b  = (const float*)d_in[3];
    const float* x1_k  = (const float*)d_in[4];
    const float* x1_b  = (const float*)d_in[5];
    const float* c51_k = (const float*)d_in[6];
    const float* c51_b = (const float*)d_in[7];
    const float* c15_k = (const float*)d_in[8];
    const float* c15_b = (const float*)d_in[9];
    const float* c55_k = (const float*)d_in[10];
    const float* c55_b = (const float*)d_in[11];
    const float* x2_k  = (const float*)d_in[12];
    const float* x2_b  = (const float*)d_in[13];
    const float* y17_k = (const float*)d_in[14];
    const float* y17_b = (const float*)d_in[15];
    const float* y71_k = (const float*)d_in[16];
    const float* y71_b = (const float*)d_in[17];
    const float* yc_k  = (const float*)d_in[18];
    const float* yc_b  = (const float*)d_in[19];
    const float* d1_k  = (const float*)d_in[20];
    const float* d2_k  = (const float*)d_in[21];
    const float* h1_w  = (const float*)d_in[22];
    const float* h1_b  = (const float*)d_in[23];
    const float* h2_w  = (const float*)d_in[24];
    const float* h2_b  = (const float*)d_in[25];
    const float* h3_w  = (const float*)d_in[26];
    const float* h3_b  = (const float*)d_in[27];

    float* ws  = (float*)d_ws;
    float* out = (float*)d_out;
    float* cs  = out + OUT0;

    hipLaunchKernelGGL(prep_kernel, dim3(33), dim3(256), 0, stream,
        inp, mat, w1_k, w1_b, x1_k, x1_b, y17_k, y17_b, y71_k, y71_b,
        yc_k, yc_b, d1_k, d2_k, h1_w, h1_b, h2_w, h2_b, h3_w, h3_b, ws);
    hipLaunchKernelGGL(fista_kernel, dim3(96), dim3(576), 0, stream, ws, cs);
    hipLaunchKernelGGL(c51c15_kernel, dim3(576), dim3(256), 0, stream,
        cs, c51_k, c51_b, c15_k, c15_b, ws + X2_OFF);
    hipLaunchKernelGGL(c55out_kernel, dim3(648), dim3(256), 0, stream,
        ws + X2_OFF, c55_k, c55_b, ws, x2_k, x2_b, out);
}

// Round 12
// 336.305 us; speedup vs baseline: 1.1446x; 1.0070x over previous
//
#include <hip/hip_runtime.h>
#include <math.h>

#define LEAKY(x) ((x) >= 0.f ? (x) : 0.3f*(x))

// ---- workspace float offsets ----
#define G_OFF   0         // 648     extracted g~ (72x9)
#define IM_OFF  648       // 7776    im (b,ch,81)
#define LAM_OFF 8424      // 32      lambda per batch
#define WB_OFF  8456      // 2592    w branch (b,81)
#define YBR_OFF 11048     // 82944   y branch (b,81,32)
#define X2_OFF  757544    // 331776  conv15 out (b,18,18,32)

#define OUT0 106272       // elements in output 0; cs_out follows

// ======================= prep =======================
__global__ __launch_bounds__(256) void prep_kernel(
    const float* __restrict__ inp, const float* __restrict__ mat,
    const float* __restrict__ w1_k, const float* __restrict__ w1_b,
    const float* __restrict__ x1_k, const float* __restrict__ x1_b,
    const float* __restrict__ y17_k, const float* __restrict__ y17_b,
    const float* __restrict__ y71_k, const float* __restrict__ y71_b,
    const float* __restrict__ yc_k, const float* __restrict__ yc_b,
    const float* __restrict__ d1_k, const float* __restrict__ d2_k,
    const float* __restrict__ h1_w, const float* __restrict__ h1_b,
    const float* __restrict__ h2_w, const float* __restrict__ h2_b,
    const float* __restrict__ h3_w, const float* __restrict__ h3_b,
    float* __restrict__ ws)
{
    int t = threadIdx.x;
    if (blockIdx.x == 0) {
        // extract separable factor: g[i][a] = mat[i*72, a*9] / sqrt(mat[0,0])
        float rs = rsqrtf(mat[0]);
        for (int u = t; u < 648; u += 256) {
            int i = u / 9, a = u % 9;
            ws[G_OFF + u] = mat[(size_t)(i*72)*81 + a*9] * rs;
        }
        return;
    }
    int b = blockIdx.x - 1;
    __shared__ float sin_[243];
    __shared__ float cm[27];
    __shared__ float cat[5184];
    __shared__ float z1[108];
    __shared__ float z2[24];
    __shared__ float v1[24];
    __shared__ float v2[12];

    const float BN  = 1.0f / sqrtf(1.001f);
    const float BN2 = BN * BN;

    for (int u = t; u < 243; u += 256) sin_[u] = inp[b*243 + u];
    __syncthreads();

    // w branch (t<81), colmax (81..107), d1 conv (128..235)
    if (t < 81) {
        float s = w1_b[0];
        for (int i = 0; i < 3; ++i) s += sin_[t*3+i] * w1_k[i];
        ws[WB_OFF + b*81 + t] = LEAKY(s);
    } else if (t < 108) {
        int u = t - 81;                       // c*3+ch
        float m = 0.f;
        for (int r = 0; r < 9; ++r) m = fmaxf(m, fabsf(sin_[r*27 + u]));
        cm[u] = 0.001f + m;
    }
    if (t >= 128 && t < 236) {
        int u = t - 128;                      // oy*36 + ox*12 + o
        int o = u % 12, ox = (u/12) % 3, oy = u/36;
        float s = 0.f;
        for (int kh = 0; kh < 5; ++kh) {
            int iy = oy*3 - 1 + kh;
            if (iy < 0 || iy > 8) continue;
            for (int kw = 0; kw < 5; ++kw) {
                int ix = ox*3 - 1 + kw;
                if (ix < 0 || ix > 8) continue;
                for (int i = 0; i < 3; ++i)
                    s += sin_[(iy*9+ix)*3 + i] * d1_k[((kh*5+kw)*3 + i)*12 + o];
            }
        }
        z1[u] = LEAKY(BN2 * s);
    }
    __syncthreads();

    // im = leaky(conv1x1(inp / colmax)) ; layout (b,ch,81)
    if (t < 243) {
        int o = t / 81, p = t % 81;
        int c = p % 9;
        float s = x1_b[o];
        for (int i = 0; i < 3; ++i)
            s += (sin_[p*3+i] / cm[c*3+i]) * x1_k[i*3 + o];
        ws[IM_OFF + (b*3 + o)*81 + p] = LEAKY(s);
    }
    __syncthreads();

    // d2 conv: 3x3x12 -> 1x1x24 (kernel rows/cols 1..3 valid)
    if (t < 24) {
        float s = 0.f;
        for (int kh = 1; kh < 4; ++kh)
            for (int kw = 1; kw < 4; ++kw)
                for (int i = 0; i < 12; ++i)
                    s += z1[((kh-1)*3 + (kw-1))*12 + i] * d2_k[((kh*5+kw)*12 + i)*24 + t];
        z2[t] = LEAKY(BN * s);
    }
    __syncthreads();
    if (t < 24) {
        float s = h1_b[t];
        for (int i = 0; i < 24; ++i) s += z2[i] * h1_w[i*24 + t];
        v1[t] = s;
    }
    __syncthreads();
    if (t < 12) {
        float s = h2_b[t];
        for (int i = 0; i < 24; ++i) s += v1[i] * h2_w[i*12 + t];
        v2[t] = s;
    }
    __syncthreads();
    if (t == 0) {
        float s = h3_b[0];
        for (int i = 0; i < 12; ++i) s += v2[i] * h3_w[i];
        ws[LAM_OFF + b] = 0.01f / (1.f + expf(-s));   // 0.1*sigmoid * 0.1
    }

    // y branch: cat = [y1(32) | y2(32)] per position
    for (int u = t; u < 5184; u += 256) {
        int pos = u / 64, i = u % 64;
        int r = pos / 9, c = pos % 9;
        float s;
        if (i < 32) {
            s = y17_b[i];
            for (int kw = 0; kw < 7; ++kw) {
                int cc = c - 3 + kw;
                if (cc < 0 || cc > 8) continue;
                for (int ii = 0; ii < 3; ++ii)
                    s += sin_[(r*9+cc)*3 + ii] * y17_k[(kw*3+ii)*32 + i];
            }
        } else {
            int i2 = i - 32;
            s = y71_b[i2];
            for (int kh = 0; kh < 7; ++kh) {
                int rr = r - 3 + kh;
                if (rr < 0 || rr > 8) continue;
                for (int ii = 0; ii < 3; ++ii)
                    s += sin_[(rr*9+c)*3 + ii] * y71_k[(kh*3+ii)*32 + i2];
            }
        }
        cat[pos*64 + i] = s;
    }
    __syncthreads();
    for (int u = t; u < 2592; u += 256) {
        int pos = u / 32, o = u % 32;
        float s = yc_b[o];
        for (int i = 0; i < 64; ++i) s += cat[pos*64 + i] * yc_k[i*32 + o];
        ws[YBR_OFF + (b*81 + pos)*32 + o] = LEAKY(s);
    }
}

// ======================= FISTA =======================
// 576 threads = 9 waves; t = j*8+gg; Toeplitz band both sides; ONE barrier
// per iteration with wave-private R + double-buffered SPm (R11 skeleton,
// hardware-verified: VGPR 52, 149us).
//
// R12 changes (both band-verified):
//  - SPm set stride 108 -> 120: reduce-read banks become
//    (12*rb + 16*rh + ra) mod 32 -- three 9-wide groups tiling at 0/12/24
//    (was 28-spaced overlap, 3-4 way). Store float4 starts (24*row+12*gg)
//    cover all 32 banks exactly.
//  - spB (b=8 S-partials) computed/stored ONLY for waves w>=7: column-
//    Toeplitz band means S[.][8] receives contributions only from waves
//    7,8; the reduce for row 8 reads only those sets. Waves 0-6's spB was
//    dead work (18 inst/iter each). Wave-uniform branch: DPP-safe.

#define DPP_XOR1 0xB1   // quad_perm {1,0,3,2}
#define DPP_XOR2 0x4E   // quad_perm {2,3,0,1}
#define DPP_HM   0x141  // row_half_mirror (cross-quad within 8; quads uniform)
#define DPP_ROR8 0x128  // row_ror:8 == lane xor 8 within 16-lane row

#define SPS    120      // set stride (floats); 36 sets per half
#define SPHALF (36*SPS)

template<int CTRL>
__device__ __forceinline__ float dppadd(float v) {
    return v + __int_as_float(__builtin_amdgcn_update_dpp(
        0, __float_as_int(v), CTRL, 0xF, 0xF, true));
}

#define STEPMID(s,sm,sp) { \
    float re = gm*q##sm + g0*q##s + gp*q##sp; \
    float wv = Yv##s + re; \
    float cl = fminf(fmaxf(wv, -lam), lam); \
    float yn = wv - cl; \
    float yx = yn + cmom*(yn - Yl##s); \
    Yl##s = yn; Yv##s = yx; \
    u##sm += yx*gm; u##s += yx*g0; u##sp += yx*gp; }
#define STEP0 { \
    float re = g0*q0 + gp*q1; \
    float wv = Yv0 + re; \
    float cl = fminf(fmaxf(wv, -lam), lam); \
    float yn = wv - cl; \
    float yx = yn + cmom*(yn - Yl0); \
    Yl0 = yn; Yv0 = yx; \
    u0 += yx*g0; u1 += yx*gp; }
#define STEP8 { \
    float re = gm*q7 + g0*q8; \
    float wv = Yv8 + re; \
    float cl = fminf(fmaxf(wv, -lam), lam); \
    float yn = wv - cl; \
    float yx = yn + cmom*(yn - Yl8); \
    Yl8 = yn; Yv8 = yx; \
    u7 += yx*gm; u8 += yx*g0; }

// T butterfly over g-groups + spA fold (all waves)
#define TSPA(a) { float v = u##a; \
    v = dppadd<DPP_XOR1>(v); v = dppadd<DPP_XOR2>(v); v = dppadd<DPP_HM>(v); \
    tt_##a = v; \
    spA_##a = dppadd<DPP_ROR8>(v*Gjg); }
// spB fold (only waves w>=7 execute this)
#define TSPB(a) spB_##a = dppadd<DPP_ROR8>(tt_##a*Gj8);

#define QT3(a) float q##a = cmc*rm_##a + c0c*r0_##a + cpc*rp_##a;

#define OUTW(s) cs_out[(size_t)(b*5184 + (8*s+gg)*72 + j)*3 + ch] = Yl##s;

__global__ __launch_bounds__(576, 3) void fista_kernel(
    const float* __restrict__ ws, float* __restrict__ cs_out)
{
    __shared__ __align__(16) float SPm[2*SPHALF];  // double-buffered partial sets
    __shared__ __align__(16) float Rpriv[9*36];    // per-wave rows {w-1,w,w+1} x 12

    int t = threadIdx.x;
    int b = blockIdx.x / 3, ch = blockIdx.x % 3;
    const float* g = ws + G_OFF;
    float lam = ws[LAM_OFF + b];

    int j = t >> 3, gg = t & 7;      // column j, row-group gg (i = 8s+gg)
    int l = t & 63;                  // lane in wave
    int w = t >> 6;                  // wave index = j>>3
    int rr = j & 7;                  // j = 8w + rr

    // ---- row-side Toeplitz G registers ----
    float gm = g[(gg + 8)*9 + 0];    // f(gg+8)
    float g0 = g[gg*9 + 0];          // f(gg)
    float gp = g[gg*9 + 1];          // f(gg-8)

    // ---- column-side Toeplitz coeffs (qt band) ----
    float cmc = (w > 0) ? g[(rr + 8)*9 + 0] : 0.f;   // f(rr+8), b=w-1
    float c0c = g[rr*9 + 0];                          // f(rr),   b=w
    float cpc = (w < 8) ? g[rr*9 + 1] : 0.f;          // f(rr-8), b=w+1

    float Gjg = g[j*9 + gg];         // g[j][gg]  (TSP store side)
    float Gj8 = g[j*9 + 8];          // g[j][8]

    // ---- R-compute role (lanes 0..53 of each wave) ----
    int r3 = l / 18, rrem = l % 18, ra = rrem >> 1, rh = rrem & 1;
    bool ract = (l < 54);
    int rb = w - 1 + r3;                       // target R row b
    bool rbval = ract && (rb >= 0) && (rb <= 8);
    int rbc = rb < 0 ? 0 : (rb > 8 ? 8 : rb);  // clamped for addressing
    int slotc = rbc*12 + ra;
    int wmv = rbc > 0 ? rbc - 1 : 0;           // band waves (clamped + masked)
    int wpv = rbc < 8 ? rbc + 1 : 8;
    float mmsk = (rbc > 0) ? 1.f : 0.f;
    float mpsk = (rbc < 8) ? 1.f : 0.f;
    int p0 = rh*2;                             // this lane's pp pair {p0, p0+1}
    float im_reg = rbval ? ws[IM_OFF + (b*3 + ch)*81 + ra*9 + rb] : 0.f;

    // init private R = im (wave-private: no barrier needed)
    if (ract && rh == 0) Rpriv[w*36 + r3*12 + ra] = rbval ? im_reg : 0.f;

    float Yv0=0,Yv1=0,Yv2=0,Yv3=0,Yv4=0,Yv5=0,Yv6=0,Yv7=0,Yv8=0;
    float Yl0=0,Yl1=0,Yl2=0,Yl3=0,Yl4=0,Yl5=0,Yl6=0,Yl7=0,Yl8=0;
    float tk = 1.f;

    for (int it = 0; it < 100; ++it) {
        float tn = 0.5f*(1.f + sqrtf(1.f + 4.f*tk*tk));
        float cmom = (tk - 1.f) / tn;
        tk = tn;

        // ---- qt[a]: 3-term band over this wave's private R rows
        const float* Rw = Rpriv + w*36;
        float4 mv0 = *(const float4*)(Rw);
        float4 mv1 = *(const float4*)(Rw + 4);
        float  mv2 = Rw[8];
        float rm_0=mv0.x, rm_1=mv0.y, rm_2=mv0.z, rm_3=mv0.w,
              rm_4=mv1.x, rm_5=mv1.y, rm_6=mv1.z, rm_7=mv1.w, rm_8=mv2;
        float4 zv0 = *(const float4*)(Rw + 12);
        float4 zv1 = *(const float4*)(Rw + 16);
        float  zv2 = Rw[20];
        float r0_0=zv0.x, r0_1=zv0.y, r0_2=zv0.z, r0_3=zv0.w,
              r0_4=zv1.x, r0_5=zv1.y, r0_6=zv1.z, r0_7=zv1.w, r0_8=zv2;
        float4 pv0 = *(const float4*)(Rw + 24);
        float4 pv1 = *(const float4*)(Rw + 28);
        float  pv2 = Rw[32];
        float rp_0=pv0.x, rp_1=pv0.y, rp_2=pv0.z, rp_3=pv0.w,
              rp_4=pv1.x, rp_5=pv1.y, rp_6=pv1.z, rp_7=pv1.w, rp_8=pv2;
        QT3(0) QT3(1) QT3(2) QT3(3) QT3(4) QT3(5) QT3(6) QT3(7) QT3(8)

        // ---- y-update for 9 owned rows + u partials (3-term band)
        float u0=0,u1=0,u2=0,u3=0,u4=0,u5=0,u6=0,u7=0,u8=0;
        STEP0
        STEPMID(1,0,2) STEPMID(2,1,3) STEPMID(3,2,4) STEPMID(4,3,5)
        STEPMID(5,4,6) STEPMID(6,5,7) STEPMID(7,6,8)
        STEP8
        if (it == 99) break;

        // ---- T butterfly + spA fold (all waves); spB only for w>=7
        float tt_0,tt_1,tt_2,tt_3,tt_4,tt_5,tt_6,tt_7,tt_8;
        float spA_0,spA_1,spA_2,spA_3,spA_4,spA_5,spA_6,spA_7,spA_8;
        TSPA(0) TSPA(1) TSPA(2) TSPA(3) TSPA(4) TSPA(5) TSPA(6) TSPA(7) TSPA(8)

        // ---- store partial sets into parity buffer
        float* SP = SPm + (it & 1)*SPHALF;
        int setb = (w*4 + (l >> 4))*SPS;
        if ((l & 8) == 0) {
            float* d = SP + setb + gg*12;
            ((float4*)d)[0] = make_float4(spA_0,spA_1,spA_2,spA_3);
            ((float4*)d)[1] = make_float4(spA_4,spA_5,spA_6,spA_7);
            d[8] = spA_8;
        }
        if (w >= 7) {
            float spB_0,spB_1,spB_2,spB_3,spB_4,spB_5,spB_6,spB_7,spB_8;
            TSPB(0) TSPB(1) TSPB(2) TSPB(3) TSPB(4) TSPB(5) TSPB(6) TSPB(7) TSPB(8)
            if ((l & 8) == 0 && gg == 0) {
                float* d2 = SP + setb + 96;
                ((float4*)d2)[0] = make_float4(spB_0,spB_1,spB_2,spB_3);
                ((float4*)d2)[1] = make_float4(spB_4,spB_5,spB_6,spB_7);
                d2[8] = spB_8;
            }
        }
        __syncthreads();   // the ONLY barrier in the loop

        // ---- per-wave private R rows from SPm band
        if (ract) {
            const float* S = SPm + (it & 1)*SPHALF;
            float s = S[(rbc*4 + p0)*SPS + slotc] + S[(rbc*4 + p0+1)*SPS + slotc]
               + mmsk*(S[(wmv*4 + p0)*SPS + slotc] + S[(wmv*4 + p0+1)*SPS + slotc])
               + mpsk*(S[(wpv*4 + p0)*SPS + slotc] + S[(wpv*4 + p0+1)*SPS + slotc]);
            s = dppadd<DPP_XOR1>(s);
            if (rh == 0)
                Rpriv[w*36 + r3*12 + ra] = rbval ? (im_reg - s) : 0.f;
        }
    }

    // ---- output: rows 8s+gg of column j
    OUTW(0) OUTW(1) OUTW(2) OUTW(3) OUTW(4) OUTW(5) OUTW(6) OUTW(7) OUTW(8)
}

// ======================= fused c51 + c15, ROW-SPLIT =======================
// Block = (b, oy) -> 576 blocks; x1 row (2.3KB LDS) computed and consumed
// in-block. Hardware-verified R10/R11 (steady-state not in slow top-5).
__global__ __launch_bounds__(256) void c51c15_kernel(
    const float* __restrict__ cs, const float* __restrict__ k51,
    const float* __restrict__ b51, const float* __restrict__ k15,
    const float* __restrict__ b15, float* __restrict__ x2out)
{
    __shared__ float x1s[36*16];      // one x1 row
    int t = threadIdx.x;
    int b = blockIdx.x / 18, oy = blockIdx.x % 18;

    // stage 1: x1 row iy1 = 2*oy; input cs rows 4*oy-1+kh
    for (int u = t; u < 36*16; u += 256) {
        int o = u & 15, ox = u >> 4;
        float s = b51[o];
        int ix = ox*2;
        for (int kh = 0; kh < 5; ++kh) {
            int iy = oy*4 - 1 + kh;
            if (iy < 0 || iy >= 72) continue;
            const float* p = cs + ((size_t)(b*72 + iy)*72 + ix)*3;
            const float* kk = k51 + kh*48 + o;
            s += p[0]*kk[0] + p[1]*kk[16] + p[2]*kk[32];
        }
        x1s[u] = s;
    }
    __syncthreads();

    // stage 2: x2 row oy (18 ox x 32 o)
    for (int u = t; u < 18*32; u += 256) {
        int o = u & 31, ox = u >> 5;
        float s = b15[o];
        for (int kw = 0; kw < 5; ++kw) {
            int ix = ox*2 - 1 + kw;
            if (ix < 0 || ix >= 36) continue;
            const float* p = x1s + ix*16;
            const float* kk = k15 + kw*512 + o;
            for (int i = 0; i < 16; ++i) s += p[i]*kk[i*32];
        }
        x2out[((size_t)(b*18 + oy)*18 + ox)*32 + o] = s;
    }
}

// ======================= fused c55 + x2conv + out =======================
// Block = 256 threads = 4 positions x 64 channels; grid = 648.
// Hardware-verified R9-R11.
__global__ __launch_bounds__(256) void c55out_kernel(
    const float* __restrict__ x2g, const float* __restrict__ k55,
    const float* __restrict__ b55, const float* __restrict__ ws,
    const float* __restrict__ x2_k, const float* __restrict__ x2_b,
    float* __restrict__ out)
{
    __shared__ float x3s[4][64];
    int t = threadIdx.x;
    int lp = t >> 6;                      // local position 0..3
    int o  = t & 63;
    int pg = blockIdx.x*4 + lp;           // global position
    int b  = pg / 81, rc = pg % 81;
    int r  = rc / 9,  c  = rc % 9;

    // phase 1: c55 at (b, r, c) channel o
    {
        float s = b55[o];
        for (int kh = 0; kh < 5; ++kh) {
            int iy = r*2 - 1 + kh;
            if (iy < 0 || iy >= 18) continue;
            for (int kw = 0; kw < 5; ++kw) {
                int ix = c*2 - 1 + kw;
                if (ix < 0 || ix >= 18) continue;
                const float* p = x2g + ((size_t)(b*18 + iy)*18 + ix)*32;
                const float* kk = k55 + (kh*5+kw)*2048 + o;
                for (int i = 0; i < 32; ++i) s += p[i]*kk[i*64];
            }
        }
        x3s[lp][o] = s;
    }
    __syncthreads();

    // phase 2: 41 outputs per position (164 active threads)
    if (t < 4*41) {
        int lp2 = t / 41, q = t % 41;
        int pg2 = blockIdx.x*4 + lp2;
        int b2  = pg2 / 81, rc2 = pg2 % 81;
        float val;
        if (q == 0) {
            val = ws[WB_OFF + b2*81 + rc2];
        } else if (q <= 8) {
            int o2 = q - 1;
            float s = x2_b[o2];
            for (int i = 0; i < 64; ++i) s += x3s[lp2][i]*x2_k[i*8 + o2];
            val = LEAKY(s);
        } else {
            val = ws[YBR_OFF + (size_t)(b2*81 + rc2)*32 + (q - 9)];
        }
        out[(size_t)pg2*41 + q] = val;
    }
}

// ======================= launch =======================
extern "C" void kernel_launch(void* const* d_in, const int* in_sizes, int n_in,
                              void* d_out, int out_size, void* d_ws, size_t ws_size,
                              hipStream_t stream) {
    const float* inp   = (const float*)d_in[0];
    const float* mat   = (const float*)d_in[1];
    const float* w1_k  = (const float*)d_in[2];
    const float* w1_b  = (const float*)d_in[3];
    const float* x1_k  = (const float*)d_in[4];
    const float* x1_b  = (const float*)d_in[5];
    const float* c51_k = (const float*)d_in[6];
    const float* c51_b = (const float*)d_in[7];
    const float* c15_k = (const float*)d_in[8];
    const float* c15_b = (const float*)d_in[9];
    const float* c55_k = (const float*)d_in[10];
    const float* c55_b = (const float*)d_in[11];
    const float* x2_k  = (const float*)d_in[12];
    const float* x2_b  = (const float*)d_in[13];
    const float* y17_k = (const float*)d_in[14];
    const float* y17_b = (const float*)d_in[15];
    const float* y71_k = (const float*)d_in[16];
    const float* y71_b = (const float*)d_in[17];
    const float* yc_k  = (const float*)d_in[18];
    const float* yc_b  = (const float*)d_in[19];
    const float* d1_k  = (const float*)d_in[20];
    const float* d2_k  = (const float*)d_in[21];
    const float* h1_w  = (const float*)d_in[22];
    const float* h1_b  = (const float*)d_in[23];
    const float* h2_w  = (const float*)d_in[24];
    const float* h2_b  = (const float*)d_in[25];
    const float* h3_w  = (const float*)d_in[26];
    const float* h3_b  = (const float*)d_in[27];

    float* ws  = (float*)d_ws;
    float* out = (float*)d_out;
    float* cs  = out + OUT0;

    hipLaunchKernelGGL(prep_kernel, dim3(33), dim3(256), 0, stream,
        inp, mat, w1_k, w1_b, x1_k, x1_b, y17_k, y17_b, y71_k, y71_b,
        yc_k, yc_b, d1_k, d2_k, h1_w, h1_b, h2_w, h2_b, h3_w, h3_b, ws);
    hipLaunchKernelGGL(fista_kernel, dim3(96), dim3(576), 0, stream, ws, cs);
    hipLaunchKernelGGL(c51c15_kernel, dim3(576), dim3(256), 0, stream,
        cs, c51_k, c51_b, c15_k, c15_b, ws + X2_OFF);
    hipLaunchKernelGGL(c55out_kernel, dim3(648), dim3(256), 0, stream,
        ws + X2_OFF, c55_k, c55_b, ws, x2_k, x2_b, out);
}